// Round 1
// baseline (177.925 us; speedup 1.0000x reference)
//
#include <hip/hip_runtime.h>

// MRPCEN: multi-rate PCEN.
//   x: (B=16, F=128, T=4096) f32; alpha_log/delta_log/r_log: (F,) f32
//   out: (B, 4, F, T) f32
// m[b,f,0]=x[b,f,0]; m[t]=(1-s)m[t-1]+s x[t]  (4 s-values, compile-time consts)
// out = (x*(EPS+m)^(-alpha) + delta)^r - delta^r
//
// v2: 256-thread block per (b,f) row; thread owns 16 CONTIGUOUS elements
// (t = 16*tid .. 16*tid+15). Decoupled scan, now only 2.3 levels:
//   16-step local recurrence (zero init) -> 64-lane wave scan (decay omn^16)
//   -> 4-wave LDS combine (decay omn^1024), ONE barrier, <=3-iter carry loop.
// Rationale vs v1 (1024-thr block, 4 elem/thr, 164.7 us):
//   - scan/carry/exp2 overhead amortized over 64 outputs/thread, not 16
//   - 6 waves/SIMD resident (launch_bounds 256,6) vs 4 -> latency hiding
//   - barrier scope 4 waves vs 16; carry chain 3 steps vs 15
// Initial condition folded by seeding carry with x[0] ((1-s)x0+s*x0=x0).
//
// NOTE: no <math.h> include — glibc's __MATHCALL declares __exp2f etc. and
// collides with HIP device intrinsics. Use __builtin_amdgcn_* directly.

#define EPS_C 1e-5f

__device__ __forceinline__ float fexp2(float v) { return __builtin_amdgcn_exp2f(v); }
__device__ __forceinline__ float flog2(float v) { return __builtin_amdgcn_logf(v); }
__device__ __forceinline__ float fpow(float a, float b) { return fexp2(b * flog2(a)); }
__device__ __forceinline__ float fexp(float v) { return fexp2(v * 1.44269504f); }

__global__ __launch_bounds__(256, 6)
void pcen_kernel(const float* __restrict__ x,
                 const float* __restrict__ alpha_log,
                 const float* __restrict__ delta_log,
                 const float* __restrict__ r_log,
                 float* __restrict__ out)
{
    const int row  = blockIdx.x;          // b*128 + f
    const int f    = row & 127;
    const int b    = row >> 7;
    const int tid  = threadIdx.x;         // 0..255
    const int lane = tid & 63;
    const int w    = tid >> 6;            // wave id 0..3

    __shared__ float wq[4][4];            // per-s, per-wave inclusive scan tails
    __shared__ float sh_x0;

    // 16 contiguous elements per thread: 4x float4 at 64B stride per instr.
    const float4* __restrict__ xrow4 = (const float4*)(x + (size_t)row * 4096);
    float xs[16];
#pragma unroll
    for (int k = 0; k < 4; ++k) {
        float4 v = xrow4[4 * tid + k];
        xs[4*k+0] = v.x; xs[4*k+1] = v.y; xs[4*k+2] = v.z; xs[4*k+3] = v.w;
    }
    if (tid == 0) sh_x0 = xs[0];

    // s-values from module constants (const-folded by the compiler)
    const float Tv[4] = {0.015f, 0.06f, 0.25f, 1.0f};
    float s_arr[4], omn_arr[4];
#pragma unroll
    for (int i = 0; i < 4; ++i) {
        float t  = Tv[i] * 86.1328125f;   // 44100/512
        float t2 = t * t;
        float s  = (__builtin_sqrtf(1.0f + 4.0f * t2) - 1.0f) / (2.0f * t2);
        s_arr[i]   = s;
        omn_arr[i] = 1.0f - s;
    }

    // Phase 1: per-s 16-step local recurrence + 64-lane wave scan (no barrier yet)
    float qxv[4];
#pragma unroll
    for (int i = 0; i < 4; ++i) {
        const float s = s_arr[i], omn = omn_arr[i];
        // local 16-element recurrence, zero initial state
        float p = 0.0f;
#pragma unroll
        for (int j = 0; j < 16; ++j) p = fmaf(omn, p, s * xs[j]);
        // wave-level inclusive scan of segment outputs, segment decay omn^16
        float c = omn * omn;               // omn^2
        c = c * c; c = c * c; c = c * c;   // omn^16
        float q = p;
#pragma unroll
        for (int k = 0; k < 6; ++k) {
            int d = 1 << k;
            float tsh = __shfl_up(q, d);
            if (lane >= d) q = fmaf(c, tsh, q);
            c = c * c;
        }
        float qx = __shfl_up(q, 1);        // within-wave exclusive
        if (lane == 0) qx = 0.0f;
        qxv[i] = qx;
        if (lane == 63) wq[i][w] = q;
    }

    // Per-F parameters (block-uniform -> scalarized); overlap with barrier
    const float al = alpha_log[f], dlg = delta_log[f], rl = r_log[f];
    const float nalpha  = -fexp(al);
    const float delta   =  fexp(dlg);
    const float r       =  fexp(rl);
    const float delta_r =  fexp(r * dlg); // delta^r = exp(r*log(delta))

    __syncthreads();                       // the only barrier
    const float x0 = sh_x0;

    float4* __restrict__ out4 = (float4*)out;

#pragma unroll
    for (int i = 0; i < 4; ++i) {
        const float s = s_arr[i], omn = omn_arr[i];
        const float l2omn = flog2(omn);
        const float Dw = fexp2(1024.0f * l2omn);      // omn^1024 (wave decay)
        // carry entering this wave; seed with M(-1)=x0 so m[0]=x[0] exactly
        float Q = x0;
        for (int v = 0; v < w; ++v) Q = fmaf(Dw, Q, wq[i][v]);  // <=3 iters
        // carry entering this thread's 16-elem segment
        const float dlane = fexp2((float)(16 * lane) * l2omn);  // omn^(16*lane)
        float m = fmaf(dlane, Q, qxv[i]);
        // replay recurrence from true carry; pcen + store per float4 chunk
        const size_t obase4 = ((size_t)((b * 4 + i) * 128 + f)) * 1024 + 4 * tid;
#pragma unroll
        for (int k = 0; k < 4; ++k) {
            float4 o;
            m = fmaf(omn, m, s * xs[4*k+0]);
            o.x = fpow(fmaf(xs[4*k+0], fpow(EPS_C + m, nalpha), delta), r) - delta_r;
            m = fmaf(omn, m, s * xs[4*k+1]);
            o.y = fpow(fmaf(xs[4*k+1], fpow(EPS_C + m, nalpha), delta), r) - delta_r;
            m = fmaf(omn, m, s * xs[4*k+2]);
            o.z = fpow(fmaf(xs[4*k+2], fpow(EPS_C + m, nalpha), delta), r) - delta_r;
            m = fmaf(omn, m, s * xs[4*k+3]);
            o.w = fpow(fmaf(xs[4*k+3], fpow(EPS_C + m, nalpha), delta), r) - delta_r;
            out4[obase4 + k] = o;
        }
    }
}

extern "C" void kernel_launch(void* const* d_in, const int* in_sizes, int n_in,
                              void* d_out, int out_size, void* d_ws, size_t ws_size,
                              hipStream_t stream) {
    const float* x  = (const float*)d_in[0];
    const float* al = (const float*)d_in[1];
    const float* dl = (const float*)d_in[2];
    const float* rl = (const float*)d_in[3];
    float* out = (float*)d_out;
    const int rows = in_sizes[0] / 4096;   // B*F = 2048
    pcen_kernel<<<rows, 256, 0, stream>>>(x, al, dl, rl, out);
}